// Round 7
// baseline (106.293 us; speedup 1.0000x reference)
//
#include <hip/hip_runtime.h>

// Problem constants (fixed by setup_inputs): B=16, N=3000, M=300, L=80, K=4
#define BB 16
#define NN 3000
#define MM 300
#define LL 80
#define KK 4
#define IOU_THRESH 0.6f

typedef unsigned long long u64;

struct Box { float x1, y1, x2, y2, area; };

__device__ __forceinline__ Box to_xyxy(float4 b) {
#pragma clang fp contract(off)
    Box r;
    r.x1 = b.x - 0.5f * b.z;
    r.y1 = b.y - 0.5f * b.w;
    r.x2 = b.x + 0.5f * b.z;
    r.y2 = b.y + 0.5f * b.w;
    r.area = (r.x2 - r.x1) * (r.y2 - r.y1);
    return r;
}

// Must be bitwise-identical between kTop and kFin (iou == gmax equality).
__device__ __forceinline__ float pair_iou(Box a, Box b) {
#pragma clang fp contract(off)
    float ltx = fmaxf(a.x1, b.x1);
    float lty = fmaxf(a.y1, b.y1);
    float rbx = fminf(a.x2, b.x2);
    float rby = fminf(a.y2, b.y2);
    float wx = fmaxf(rbx - ltx, 0.0f);
    float wy = fmaxf(rby - lty, 0.0f);
    float inter = wx * wy;
    float uni = a.area + b.area - inter;
    return inter / fmaxf(uni, 1e-9f);
}

// monotonic float <-> u32 (order-preserving bijection, finite values)
__device__ __forceinline__ unsigned int f32_to_ordered(float f) {
    unsigned int u = __float_as_uint(f);
    return (u & 0x80000000u) ? ~u : (u | 0x80000000u);
}
__device__ __forceinline__ float ordered_to_f32(unsigned int u) {
    unsigned int b = (u & 0x80000000u) ? (u & 0x7FFFFFFFu) : ~u;
    return __uint_as_float(b);
}

__device__ __forceinline__ u64 umax64(u64 a, u64 b) { return a > b ? a : b; }
__device__ __forceinline__ u64 umin64(u64 a, u64 b) { return a < b ? a : b; }

__device__ __forceinline__ u64 shfl_xor_u64(u64 v, int mask) {
    int lo = __shfl_xor((int)(unsigned)v, mask, 64);
    int hi = __shfl_xor((int)(unsigned)(v >> 32), mask, 64);
    return ((u64)(unsigned)hi << 32) | (u64)(unsigned)lo;
}

// branchless insert of k into sorted-desc 4-list
__device__ __forceinline__ void topins(u64 t[4], u64 k) {
    u64 c0 = umin64(t[0], k);
    t[0] = umax64(t[0], k);
    u64 c1 = umin64(t[1], c0);
    t[1] = umax64(t[1], c0);
    u64 c2 = umin64(t[2], c1);
    t[2] = umax64(t[2], c1);
    t[3] = umax64(t[3], c2);
}

// butterfly: top-4 of the union of all 64 lanes' sorted-desc 4-lists
__device__ __forceinline__ void wave_merge_top4(u64 t[4]) {
    #pragma unroll
    for (int s = 1; s < 64; s <<= 1) {
        u64 b0 = shfl_xor_u64(t[0], s);
        u64 b1 = shfl_xor_u64(t[1], s);
        u64 b2 = shfl_xor_u64(t[2], s);
        u64 b3 = shfl_xor_u64(t[3], s);
        u64 a0 = t[0], a1 = t[1], a2 = t[2], a3 = t[3];
        t[0] = umax64(a0, b0);
        t[1] = umax64(umin64(a0, b0), umax64(a1, b1));
        t[2] = umax64(umax64(a2, b2), umax64(umin64(a0, b1), umin64(a1, b0)));
        t[3] = umax64(umax64(a3, b3),
               umax64(umin64(a0, b2), umax64(umin64(a1, b1), umin64(a2, b0))));
    }
}

// ---------------------------------------------------------------------------
// kBin: one block per batch (proven r3 shape). Label histograms + prefix +
// bucket scatter of proposal ids (ushort) and GT row ids (ushort). Bucket
// order nondeterministic (LDS atomic cursors); all consumers order-invariant.
__global__ __launch_bounds__(256) void kBin(const int* __restrict__ pinds,
                                            const int* __restrict__ glab,
                                            unsigned short* __restrict__ pidx,
                                            int* __restrict__ pstart,
                                            int* __restrict__ pcnt,
                                            unsigned short* __restrict__ gidx,
                                            int* __restrict__ gstart,
                                            int* __restrict__ gcnt) {
    int b = blockIdx.x;
    int tid = threadIdx.x;
    __shared__ int hist[LL], cur[LL], gh[LL], gcur[LL];
    if (tid < LL) { hist[tid] = 0; gh[tid] = 0; }
    __syncthreads();
    for (int n = tid; n < NN; n += 256) atomicAdd(&hist[pinds[b * NN + n]], 1);
    for (int m = tid; m < MM; m += 256) atomicAdd(&gh[glab[b * MM + m]], 1);
    __syncthreads();
    if (tid < LL) {
        int s = 0;
        for (int j = 0; j < tid; ++j) s += hist[j];
        cur[tid] = s; pstart[b * LL + tid] = s; pcnt[b * LL + tid] = hist[tid];
        int t = 0;
        for (int j = 0; j < tid; ++j) t += gh[j];
        gcur[tid] = t; gstart[b * LL + tid] = t; gcnt[b * LL + tid] = gh[tid];
    }
    __syncthreads();
    for (int n = tid; n < NN; n += 256) {
        int l = pinds[b * NN + n];
        int pos = atomicAdd(&cur[l], 1);
        pidx[b * NN + pos] = (unsigned short)n;
    }
    for (int m = tid; m < MM; m += 256) {
        int l = glab[b * MM + m];
        int pos = atomicAdd(&gcur[l], 1);
        gidx[b * MM + pos] = (unsigned short)m;
    }
}

// ---------------------------------------------------------------------------
// kTop: one wave per GT bucket slot (proven r3 shape). Lane-strided scan of
// the label's proposal bucket (~37 entries), per-lane topins, wave butterfly
// merge. Writes exact lax.top_k top-4 (by original m), and packed GT record
// (box+area+gmax+m) in bucket order for kFin.
__global__ __launch_bounds__(256) void kTop(const float4* __restrict__ props,
                                            const int*    __restrict__ glab,
                                            const float4* __restrict__ gbox,
                                            const unsigned short* __restrict__ pidx,
                                            const int* __restrict__ pstart,
                                            const int* __restrict__ pcnt,
                                            const unsigned short* __restrict__ gidx,
                                            float*  __restrict__ topv,
                                            int*    __restrict__ topi,
                                            float4* __restrict__ grec) {
    int b = blockIdx.y;
    int wv = __builtin_amdgcn_readfirstlane((int)(threadIdx.x >> 6));
    int lane = threadIdx.x & 63;
    int g = blockIdx.x * 4 + wv;            // grid.x = 75 -> g in [0,300)
    int m = gidx[b * MM + g];
    int bm = b * MM + m;
    Box gt = to_xyxy(gbox[bm]);
    int l = glab[bm];
    int s = pstart[b * LL + l], c = pcnt[b * LL + l];

    const u64 init = ((u64)f32_to_ordered(-1.0f) << 32);
    u64 t[4] = {init, init, init, init};
    for (int i = lane; i < c; i += 64) {   // c ~ 37, usually one pass
        int n = pidx[b * NN + s + i];
        Box pb = to_xyxy(props[(size_t)b * NN + n]);
        float iou = pair_iou(gt, pb);      // all bucket entries match -> v = iou
        u64 key = ((u64)f32_to_ordered(iou) << 32) |
                  (u64)(0xFFFFFFFFu - (unsigned)n);
        topins(t, key);
    }
    wave_merge_top4(t);

    if (lane == 0) {
        float gm = ordered_to_f32((unsigned)(t[0] >> 32));
        #pragma unroll
        for (int j = 0; j < KK; ++j) {
            topv[bm * KK + j] = ordered_to_f32((unsigned)(t[j] >> 32));
            topi[bm * KK + j] = (int)(0xFFFFFFFFu - (unsigned)t[j]);
        }
        int gpos = b * MM + g;             // bucket-slot order
        grec[gpos * 2 + 0] = make_float4(gt.x1, gt.y1, gt.x2, gt.y2);
        grec[gpos * 2 + 1] = make_float4(gt.area, gm, __int_as_float(m), 0.0f);
    }
}

// ---------------------------------------------------------------------------
// kFin: one block per batch. Stages GT records into LDS; phase C: one thread
// per proposal — u64-key argmax over its label's GT bucket (ties -> smaller m
// = first occurrence), lq via bitwise iou==gmax, atomicAdd into LDS counts.
// Phase D: epilogue, one thread per GT row, float4 writes of all 4 chunks.
__global__ __launch_bounds__(256) void kFin(const float4* __restrict__ props,
                                            const int*    __restrict__ pinds,
                                            const float*  __restrict__ topv,
                                            const int*    __restrict__ topi,
                                            const float4* __restrict__ grec,
                                            const int*    __restrict__ gstart,
                                            const int*    __restrict__ gcnt,
                                            float* __restrict__ out) {
    int b = blockIdx.x;
    int tid = threadIdx.x;

    __shared__ float4 sg[MM * 2];   // staged GT records (9.6 KB)
    __shared__ int scnt[MM];        // counts, by original m
    __shared__ int gst[LL], gcn[LL];

    for (int i = tid; i < MM * 2; i += 256) sg[i] = grec[b * MM * 2 + i];
    for (int i = tid; i < MM; i += 256) scnt[i] = 0;
    if (tid < LL) {
        gst[tid] = gstart[b * LL + tid];
        gcn[tid] = gcnt[b * LL + tid];
    }
    __syncthreads();

    // Phase C
    for (int n = tid; n < NN; n += 256) {
        Box pb = to_xyxy(props[(size_t)b * NN + n]);
        int l = pinds[b * NN + n];
        int s = gst[l];
        int c = gcn[l];
        u64 key = 0;
        bool lq = false;
        for (int j = 0; j < c; ++j) {
            float4 q0 = sg[(s + j) * 2];
            float4 q1 = sg[(s + j) * 2 + 1];
            Box a;
            a.x1 = q0.x; a.y1 = q0.y; a.x2 = q0.z; a.y2 = q0.w;
            a.area = q1.x;
            float iou = pair_iou(a, pb);
            int m = __float_as_int(q1.z);
            u64 k = ((u64)f32_to_ordered(iou) << 32) |
                    (u64)(0xFFFFFFFFu - (unsigned)m);
            key = umax64(key, k);
            lq = lq || (iou == q1.y);
        }
        if (c > 0) {  // valid_prop; all scanned pairs match so best v >= 0
            float v = ordered_to_f32((unsigned)(key >> 32));
            int bm = (int)(0xFFFFFFFFu - (unsigned)key);
            if ((v >= IOU_THRESH) || lq) atomicAdd(&scnt[bm], 1);
        }
    }
    __syncthreads();

    // Phase D
    for (int m = tid; m < MM; m += 256) {
        int i = b * MM + m;
        int take = min(scnt[m], KK);
        float4 tv = ((const float4*)topv)[i];
        int4   ti = ((const int4*)topi)[i];
        float4 rows, cols, valid, sel;
        rows.x = (0 < take) ? (float)ti.x : -1.0f;
        rows.y = (1 < take) ? (float)ti.y : -1.0f;
        rows.z = (2 < take) ? (float)ti.z : -1.0f;
        rows.w = (3 < take) ? (float)ti.w : -1.0f;
        cols.x = (0 < take) ? (float)m : -1.0f;
        cols.y = (1 < take) ? (float)m : -1.0f;
        cols.z = (2 < take) ? (float)m : -1.0f;
        cols.w = (3 < take) ? (float)m : -1.0f;
        valid.x = (0 < take) ? 1.0f : 0.0f;
        valid.y = (1 < take) ? 1.0f : 0.0f;
        valid.z = (2 < take) ? 1.0f : 0.0f;
        valid.w = (3 < take) ? 1.0f : 0.0f;
        sel.x = (0 < take) ? tv.x : 0.0f;
        sel.y = (1 < take) ? tv.y : 0.0f;
        sel.z = (2 < take) ? tv.z : 0.0f;
        sel.w = (3 < take) ? tv.w : 0.0f;
        float4* o = (float4*)out;
        const int CH4 = BB * MM;  // 4800 float4s per output chunk
        o[0 * CH4 + i] = rows;
        o[1 * CH4 + i] = cols;
        o[2 * CH4 + i] = valid;
        o[3 * CH4 + i] = sel;
    }
}

extern "C" void kernel_launch(void* const* d_in, const int* in_sizes, int n_in,
                              void* d_out, int out_size, void* d_ws, size_t ws_size,
                              hipStream_t stream) {
    // inputs: 0 pred_logits_match (unused), 1 pred_boxes (unused),
    //         2 init_reference (proposals), 3 prompt_inds, 4 gt_labels,
    //         5 gt_boxes, 6 max_k (==4, hardcoded)
    const float4* props = (const float4*)d_in[2];
    const int*    pinds = (const int*)d_in[3];
    const int*    glab  = (const int*)d_in[4];
    const float4* gbox  = (const float4*)d_in[5];
    float* out = (float*)d_out;

    // ws layout (~430 KB; ws is poisoned 0xAA each iter, all slots rewritten
    // before use within this launch sequence):
    char* w = (char*)d_ws;
    float*  topv   = (float*)w;  w += (size_t)BB * MM * KK * sizeof(float);   //  76.8 KB
    int*    topi   = (int*)w;    w += (size_t)BB * MM * KK * sizeof(int);     //  76.8 KB
    float4* grec   = (float4*)w; w += (size_t)BB * MM * 2 * sizeof(float4);   // 153.6 KB
    int*    pstart = (int*)w;    w += (size_t)BB * LL * sizeof(int);          //   5.1 KB
    int*    pcnt   = (int*)w;    w += (size_t)BB * LL * sizeof(int);          //   5.1 KB
    int*    gstart = (int*)w;    w += (size_t)BB * LL * sizeof(int);          //   5.1 KB
    int*    gcnt   = (int*)w;    w += (size_t)BB * LL * sizeof(int);          //   5.1 KB
    unsigned short* pidx = (unsigned short*)w; w += (size_t)BB * NN * 2;      //  96.0 KB
    unsigned short* gidx = (unsigned short*)w;                                //   9.6 KB

    kBin<<<BB, 256, 0, stream>>>(pinds, glab, pidx, pstart, pcnt,
                                 gidx, gstart, gcnt);
    dim3 gT(MM / 4, BB);  // 75 x 16, 4 waves/block, one wave per GT bucket slot
    kTop<<<gT, 256, 0, stream>>>(props, glab, gbox, pidx, pstart, pcnt, gidx,
                                 topv, topi, grec);
    kFin<<<BB, 256, 0, stream>>>(props, pinds, topv, topi, grec,
                                 gstart, gcnt, out);
}

// Round 8
// 89.983 us; speedup vs baseline: 1.1813x; 1.1813x over previous
//
#include <hip/hip_runtime.h>

// Problem constants (fixed by setup_inputs): B=16, N=3000, M=300, L=80, K=4
#define BB 16
#define NN 3000
#define MM 300
#define LL 80
#define KK 4
#define IOU_THRESH 0.6f

typedef unsigned long long u64;

struct Box { float x1, y1, x2, y2, area; };

__device__ __forceinline__ Box to_xyxy(float4 b) {
#pragma clang fp contract(off)
    Box r;
    r.x1 = b.x - 0.5f * b.z;
    r.y1 = b.y - 0.5f * b.w;
    r.x2 = b.x + 0.5f * b.z;
    r.y2 = b.y + 0.5f * b.w;
    r.area = (r.x2 - r.x1) * (r.y2 - r.y1);
    return r;
}

// Must be bitwise-identical between kTop and kAsn (iou == gmax equality depends on it).
__device__ __forceinline__ float pair_iou(Box a, Box b) {
#pragma clang fp contract(off)
    float ltx = fmaxf(a.x1, b.x1);
    float lty = fmaxf(a.y1, b.y1);
    float rbx = fminf(a.x2, b.x2);
    float rby = fminf(a.y2, b.y2);
    float wx = fmaxf(rbx - ltx, 0.0f);
    float wy = fmaxf(rby - lty, 0.0f);
    float inter = wx * wy;
    float uni = a.area + b.area - inter;
    return inter / fmaxf(uni, 1e-9f);
}

// monotonic float <-> u32 (order-preserving bijection, finite values)
__device__ __forceinline__ unsigned int f32_to_ordered(float f) {
    unsigned int u = __float_as_uint(f);
    return (u & 0x80000000u) ? ~u : (u | 0x80000000u);
}
__device__ __forceinline__ float ordered_to_f32(unsigned int u) {
    unsigned int b = (u & 0x80000000u) ? (u & 0x7FFFFFFFu) : ~u;
    return __uint_as_float(b);
}

__device__ __forceinline__ u64 umax64(u64 a, u64 b) { return a > b ? a : b; }
__device__ __forceinline__ u64 umin64(u64 a, u64 b) { return a < b ? a : b; }

__device__ __forceinline__ u64 shfl_xor_u64(u64 v, int mask) {
    int lo = __shfl_xor((int)(unsigned)v, mask, 64);
    int hi = __shfl_xor((int)(unsigned)(v >> 32), mask, 64);
    return ((u64)(unsigned)hi << 32) | (u64)(unsigned)lo;
}

// branchless insert of k into sorted-desc 4-list
__device__ __forceinline__ void topins(u64 t[4], u64 k) {
    u64 c0 = umin64(t[0], k);
    t[0] = umax64(t[0], k);
    u64 c1 = umin64(t[1], c0);
    t[1] = umax64(t[1], c0);
    u64 c2 = umin64(t[2], c1);
    t[2] = umax64(t[2], c1);
    t[3] = umax64(t[3], c2);
}

// butterfly: top-4 of the union of all 64 lanes' sorted-desc 4-lists (all lanes get result)
__device__ __forceinline__ void wave_merge_top4(u64 t[4]) {
    #pragma unroll
    for (int s = 1; s < 64; s <<= 1) {
        u64 b0 = shfl_xor_u64(t[0], s);
        u64 b1 = shfl_xor_u64(t[1], s);
        u64 b2 = shfl_xor_u64(t[2], s);
        u64 b3 = shfl_xor_u64(t[3], s);
        u64 a0 = t[0], a1 = t[1], a2 = t[2], a3 = t[3];
        t[0] = umax64(a0, b0);
        t[1] = umax64(umin64(a0, b0), umax64(a1, b1));
        t[2] = umax64(umax64(a2, b2), umax64(umin64(a0, b1), umin64(a1, b0)));
        t[3] = umax64(umax64(a3, b3),
               umax64(umin64(a0, b2), umax64(umin64(a1, b1), umin64(a2, b0))));
    }
}

// ---------------------------------------------------------------------------
// kBin: one block per batch. Label-histogram + exclusive prefix + scatter of
// proposal indices (ushort) and GT row indices (ushort) into per-label buckets.
// Also zeroes counts. Bucket order is nondeterministic (LDS atomic cursors) but
// all downstream results are order-invariant (u64 key max / OR / int adds).
__global__ __launch_bounds__(256) void kBin(const int* __restrict__ pinds,
                                            const int* __restrict__ glab,
                                            unsigned short* __restrict__ pidx,
                                            int* __restrict__ pstart,
                                            int* __restrict__ pcnt,
                                            unsigned short* __restrict__ gidx,
                                            int* __restrict__ gstart,
                                            int* __restrict__ gcnt,
                                            int* __restrict__ counts) {
    int b = blockIdx.x;
    int tid = threadIdx.x;
    __shared__ int hist[LL], cur[LL], gh[LL], gcur[LL];
    if (tid < LL) { hist[tid] = 0; gh[tid] = 0; }
    __syncthreads();
    for (int n = tid; n < NN; n += 256) atomicAdd(&hist[pinds[b * NN + n]], 1);
    for (int m = tid; m < MM; m += 256) atomicAdd(&gh[glab[b * MM + m]], 1);
    __syncthreads();
    if (tid < LL) {
        int s = 0;
        for (int j = 0; j < tid; ++j) s += hist[j];
        cur[tid] = s; pstart[b * LL + tid] = s; pcnt[b * LL + tid] = hist[tid];
        int t = 0;
        for (int j = 0; j < tid; ++j) t += gh[j];
        gcur[tid] = t; gstart[b * LL + tid] = t; gcnt[b * LL + tid] = gh[tid];
    }
    __syncthreads();
    for (int n = tid; n < NN; n += 256) {
        int l = pinds[b * NN + n];
        int pos = atomicAdd(&cur[l], 1);
        pidx[b * NN + pos] = (unsigned short)n;
    }
    for (int m = tid; m < MM; m += 256) {
        int l = glab[b * MM + m];
        int pos = atomicAdd(&gcur[l], 1);
        gidx[b * MM + pos] = (unsigned short)m;
    }
    for (int i = tid; i < MM; i += 256) counts[b * MM + i] = 0;
}

// ---------------------------------------------------------------------------
// kTop: one wave per GT bucket position. Scans only the proposal bucket of the
// row's label (~37 entries). Writes exact lax.top_k(v,idx) top-4 (slots beyond
// the match count are padding, always masked by kC since take<=match_count),
// gmax, and a packed GT record (box+area+gmax+m) in bucket order for kAsn.
// d_out layout: floats [0,38400) GT records | [38400,57600) topv | [57600,76800) topi
__global__ __launch_bounds__(256) void kTop(const float4* __restrict__ props,
                                            const int*    __restrict__ glab,
                                            const float4* __restrict__ gbox,
                                            const unsigned short* __restrict__ pidx,
                                            const int* __restrict__ pstart,
                                            const int* __restrict__ pcnt,
                                            const unsigned short* __restrict__ gidx,
                                            float* out) {
    int b = blockIdx.y;
    int wv = __builtin_amdgcn_readfirstlane((int)(threadIdx.x >> 6));
    int lane = threadIdx.x & 63;
    int g = blockIdx.x * 4 + wv;            // grid.x = 75 -> g in [0,300)
    int m = gidx[b * MM + g];
    int bm = b * MM + m;
    Box gt = to_xyxy(gbox[bm]);
    int l = glab[bm];
    int s = pstart[b * LL + l], c = pcnt[b * LL + l];

    const u64 init = ((u64)f32_to_ordered(-1.0f) << 32);
    u64 t[4] = {init, init, init, init};
    for (int i = lane; i < c; i += 64) {   // c ~ 37, usually a single pass
        int n = pidx[b * NN + s + i];
        Box pb = to_xyxy(props[(size_t)b * NN + n]);
        float iou = pair_iou(gt, pb);      // all bucket entries match -> v = iou
        u64 key = ((u64)f32_to_ordered(iou) << 32) |
                  (u64)(0xFFFFFFFFu - (unsigned)n);
        topins(t, key);
    }
    wave_merge_top4(t);

    if (lane == 0) {
        float* topv = out + 38400;
        int*   topi = (int*)(out + 57600);
        #pragma unroll
        for (int j = 0; j < KK; ++j) {
            topv[bm * KK + j] = ordered_to_f32((unsigned)(t[j] >> 32));
            topi[bm * KK + j] = (int)(0xFFFFFFFFu - (unsigned)t[j]);
        }
        float gm = ordered_to_f32((unsigned)(t[0] >> 32));
        float4* gtb = (float4*)out;
        int gpos = b * MM + g;
        gtb[gpos * 2 + 0] = make_float4(gt.x1, gt.y1, gt.x2, gt.y2);
        gtb[gpos * 2 + 1] = make_float4(gt.area, gm, __int_as_float(m), 0.0f);
    }
}

// ---------------------------------------------------------------------------
// kAsn: one thread per proposal. Scans only the GT bucket of its label
// (~3.75 rows): best_gt via u64 key (first-occurrence argmax = min-m tie-break),
// lq via exact bitwise iou==gmax, then one atomicAdd into counts.
__global__ __launch_bounds__(256) void kAsn(const float4* __restrict__ props,
                                            const int*    __restrict__ pinds,
                                            const int* __restrict__ gstart,
                                            const int* __restrict__ gcnt,
                                            const float* __restrict__ out,
                                            int* __restrict__ counts) {
    int b = blockIdx.y;
    int n = blockIdx.x * 256 + threadIdx.x;
    if (n >= NN) return;
    float4 pr = props[(size_t)b * NN + n];
    int lbl = pinds[(size_t)b * NN + n];
    Box pb = to_xyxy(pr);
    int s = gstart[b * LL + lbl], c = gcnt[b * LL + lbl];
    const float4* gtb = (const float4*)out;

    u64 key = 0;
    bool lq = false;
    for (int j = 0; j < c; ++j) {
        int idx = (b * MM + s + j) * 2;
        float4 q0 = gtb[idx], q1 = gtb[idx + 1];
        Box a; a.x1 = q0.x; a.y1 = q0.y; a.x2 = q0.z; a.y2 = q0.w; a.area = q1.x;
        float iou = pair_iou(a, pb);
        int m = __float_as_int(q1.z);
        u64 k = ((u64)f32_to_ordered(iou) << 32) |
                (u64)(0xFFFFFFFFu - (unsigned)m);
        key = umax64(key, k);
        lq = lq || (iou == q1.y);
    }
    if (c > 0) {  // valid_prop; all scanned pairs match so best v >= 0
        float v = ordered_to_f32((unsigned)(key >> 32));
        int bm = (int)(0xFFFFFFFFu - (unsigned)key);
        if ((v >= IOU_THRESH) || lq) atomicAdd(&counts[b * MM + bm], 1);
    }
}

// ---------------------------------------------------------------------------
// kC: epilogue. Thread i reads topv/topi (back half of d_out) and counts, then
// writes the 4 output chunks. Overlapping slots (chunk2==topv, chunk3==topi
// regions) are read-before-write within the same thread; GT-record region
// (chunks 0-1) is dead after kAsn.
__global__ __launch_bounds__(256) void kC(const int* __restrict__ counts,
                                          float* out) {
    int i = blockIdx.x * 256 + threadIdx.x;  // [0, B*M)
    if (i >= BB * MM) return;
    int m = i % MM;
    int take = min(counts[i], KK);
    float4 tv = ((const float4*)(out + 38400))[i];
    int4   ti = ((const int4*)(out + 57600))[i];
    float4 rows, cols, valid, sel;
    rows.x = (0 < take) ? (float)ti.x : -1.0f;
    rows.y = (1 < take) ? (float)ti.y : -1.0f;
    rows.z = (2 < take) ? (float)ti.z : -1.0f;
    rows.w = (3 < take) ? (float)ti.w : -1.0f;
    cols.x = (0 < take) ? (float)m : -1.0f;
    cols.y = (1 < take) ? (float)m : -1.0f;
    cols.z = (2 < take) ? (float)m : -1.0f;
    cols.w = (3 < take) ? (float)m : -1.0f;
    valid.x = (0 < take) ? 1.0f : 0.0f;
    valid.y = (1 < take) ? 1.0f : 0.0f;
    valid.z = (2 < take) ? 1.0f : 0.0f;
    valid.w = (3 < take) ? 1.0f : 0.0f;
    sel.x = (0 < take) ? tv.x : 0.0f;
    sel.y = (1 < take) ? tv.y : 0.0f;
    sel.z = (2 < take) ? tv.z : 0.0f;
    sel.w = (3 < take) ? tv.w : 0.0f;
    float4* o = (float4*)out;
    const int CH4 = BB * MM;  // 4800 float4s per chunk
    o[0 * CH4 + i] = rows;
    o[1 * CH4 + i] = cols;
    o[2 * CH4 + i] = valid;
    o[3 * CH4 + i] = sel;
}

extern "C" void kernel_launch(void* const* d_in, const int* in_sizes, int n_in,
                              void* d_out, int out_size, void* d_ws, size_t ws_size,
                              hipStream_t stream) {
    // inputs: 0 pred_logits_match (unused), 1 pred_boxes (unused),
    //         2 init_reference (proposals), 3 prompt_inds, 4 gt_labels,
    //         5 gt_boxes, 6 max_k (==4, hardcoded)
    const float4* props = (const float4*)d_in[2];
    const int*    pinds = (const int*)d_in[3];
    const int*    glab  = (const int*)d_in[4];
    const float4* gbox  = (const float4*)d_in[5];
    float* out = (float*)d_out;

    // ws layout (145.3 KB total):
    char* w = (char*)d_ws;
    int*   counts = (int*)w;                 w += BB * MM * sizeof(int);      // 19200
    int*   pstart = (int*)w;                 w += BB * LL * sizeof(int);      //  5120
    int*   pcnt   = (int*)w;                 w += BB * LL * sizeof(int);      //  5120
    int*   gstart = (int*)w;                 w += BB * LL * sizeof(int);      //  5120
    int*   gcnt   = (int*)w;                 w += BB * LL * sizeof(int);      //  5120
    unsigned short* pidx = (unsigned short*)w; w += BB * NN * sizeof(short);  // 96000
    unsigned short* gidx = (unsigned short*)w;                                //  9600

    kBin<<<BB, 256, 0, stream>>>(pinds, glab, pidx, pstart, pcnt,
                                 gidx, gstart, gcnt, counts);
    dim3 gT(MM / 4, BB);  // 75 x 16, 4 waves/block, one wave per GT bucket slot
    kTop<<<gT, 256, 0, stream>>>(props, glab, gbox, pidx, pstart, pcnt, gidx, out);
    dim3 gA((NN + 255) / 256, BB);
    kAsn<<<gA, 256, 0, stream>>>(props, pinds, gstart, gcnt, out, counts);
    kC<<<(BB * MM + 255) / 256, 256, 0, stream>>>(counts, out);
}